// Round 4
// baseline (612.322 us; speedup 1.0000x reference)
//
#include <hip/hip_runtime.h>
#include <cfloat>

constexpr int BATCH = 8, NPTS = 2048;
constexpr int M = BATCH * NPTS;   // 16384 nodes
constexpr int CTXW = 515;
constexpr float KNN_EPS = 1e-3f;  // fp32 distance abs-error bound ~4e-5; 25x margin

typedef __attribute__((ext_vector_type(8))) short bf16x8;
typedef __attribute__((ext_vector_type(4))) float f32x4;

__device__ __forceinline__ float lrelu(float v) { return v > 0.0f ? v : 0.2f * v; }
__device__ __forceinline__ float b2f(short u) {
    return __uint_as_float(((unsigned int)(unsigned short)u) << 16);
}
__device__ __forceinline__ short f2bf(float f) {
    unsigned int u = __float_as_uint(f);
    return (short)((u + 0x7FFF + ((u >> 16) & 1)) >> 16);
}

__global__ void zero1(int* p) { *p = 0; }

// ---------------- ctx vector ----------------
__global__ void build_ctx(const float* __restrict__ beta, const float* __restrict__ ctxv,
                          const float* __restrict__ cond, float* __restrict__ ctx) {
    int b = blockIdx.x;
    float be = beta[b];
    for (int i = threadIdx.x; i < CTXW; i += blockDim.x) {
        float v;
        if (i == 0) v = be;
        else if (i == 1) v = sinf(be);
        else if (i == 2) v = cosf(be);
        else if (i < 259) v = ctxv[b * 256 + (i - 3)];
        else v = cond[b * 256 + (i - 259)];
        ctx[b * CTXW + i] = v;
    }
}

// fused: bias_ctx for layers 1..3; grid (14, BATCH)
__global__ __launch_bounds__(256) void ctx_bias_all(const float* __restrict__ ctx,
        const float* __restrict__ W1, const float* __restrict__ b1,
        const float* __restrict__ W2, const float* __restrict__ b2,
        const float* __restrict__ W3, const float* __restrict__ b3,
        float* __restrict__ bias1, float* __restrict__ bias2, float* __restrict__ bias3) {
    int b = blockIdx.y, blk = blockIdx.x;
    const float *W, *bv; float* out; int rowOff, F, fblk;
    if (blk < 2)      { W = W1; bv = b1; out = bias1; rowOff = 128; F = 128; fblk = blk; }
    else if (blk < 6) { W = W2; bv = b2; out = bias2; rowOff = 256; F = 256; fblk = blk - 2; }
    else              { W = W3; bv = b3; out = bias3; rowOff = 512; F = 512; fblk = blk - 6; }
    int fl = threadIdx.x >> 2, ks = threadIdx.x & 3;
    int f = fblk * 64 + fl;
    const float* c = ctx + b * CTXW;
    const float* w = W + (size_t)rowOff * F + f;
    float s = 0.f;
    for (int i = ks; i < CTXW; i += 4) s = fmaf(c[i], w[(size_t)i * F], s);
    s += __shfl_xor(s, 1);
    s += __shfl_xor(s, 2);
    if (ks == 0) out[(size_t)b * F + f] = s + bv[f];
}

// fused weight pack (transposed bf16): W1p(256x64) W2p(512x128) W3p(1024x256) Wf1p(256x512)
__global__ void pack_all(const float* __restrict__ W1, const float* __restrict__ W2,
                         const float* __restrict__ W3, const float* __restrict__ Wf1,
                         short* __restrict__ W1p, short* __restrict__ W2p,
                         short* __restrict__ W3p, short* __restrict__ Wf1p) {
    int gid = blockIdx.x * 256 + threadIdx.x;
    if (gid < 16384) {
        int j = gid >> 6, k = gid & 63;
        float v = (j < 128) ? W1[(size_t)k * 128 + j] : W1[(size_t)(64 + k) * 128 + (j - 128)];
        W1p[gid] = f2bf(v);
    } else if (gid < 81920) {
        int g = gid - 16384; int j = g >> 7, k = g & 127;
        float v = (j < 256) ? W2[(size_t)k * 256 + j] : W2[(size_t)(128 + k) * 256 + (j - 256)];
        W2p[g] = f2bf(v);
    } else if (gid < 344064) {
        int g = gid - 81920; int j = g >> 8, k = g & 255;
        float v = (j < 512) ? W3[(size_t)k * 512 + j] : W3[(size_t)(256 + k) * 512 + (j - 512)];
        W3p[g] = f2bf(v);
    } else if (gid < 475136) {
        int g = gid - 344064; int f = g >> 9, k = g & 511;
        Wf1p[g] = f2bf(Wf1[(size_t)k * 256 + f]);
    }
}

// ---------------- kNN pass 1: fp32 scan, top-9, gap-flag ambiguous nodes ----------------
// Block: 16 nodes x 16 chunks. xs packed float4(x,y,z,sq) -> 1x ds_read_b128/cand.
__global__ __launch_bounds__(256) void knn32(const float* __restrict__ x, int* __restrict__ idx,
                                             int* __restrict__ flist, int* __restrict__ fcount) {
    __shared__ __align__(16) char pool[32768];
    float4* xs4 = (float4*)pool;              // 2048*16 = 32768 B
    int b = blockIdx.y;
    const float* xb = x + (size_t)b * NPTS * 3;
    int tid = threadIdx.x;
    for (int i = tid; i < NPTS; i += 256) {
        float a0 = xb[i * 3], a1 = xb[i * 3 + 1], a2 = xb[i * 3 + 2];
        float sq = (a0 * a0 + a1 * a1) + a2 * a2;
        xs4[i] = make_float4(a0, a1, a2, sq);
    }
    __syncthreads();

    int nl = tid & 15;            // node within block
    int chunk = tid >> 4;         // candidate chunk 0..15
    int n = blockIdx.x * 16 + nl;
    float4 me = xs4[n];
    float sqn = me.w;
    float best[9];
    int bi[9];
#pragma unroll
    for (int k = 0; k < 9; ++k) { best[k] = FLT_MAX; bi[k] = 0; }
    int mbase = chunk * 128;
    int nloc = n - mbase;         // in [0,128) only if self in this chunk
    for (int i = 0; i < 128; ++i) {
        int ii = (i + chunk * 2) & 127;   // stagger: de-conflict banks across chunk groups
        int m = mbase + ii;
        float4 c = xs4[m];
        float dot = fmaf(me.x, c.x, fmaf(me.y, c.y, me.z * c.z));
        float d = fmaf(-2.0f, dot, sqn + c.w);
        if (ii != nloc && d < best[8]) {
            float cd = d; int ci = m;
#pragma unroll
            for (int j = 0; j < 9; ++j) {
                if (cd < best[j]) {
                    float td = best[j]; best[j] = cd; cd = td;
                    int ti = bi[j]; bi[j] = ci; ci = ti;
                }
            }
        }
    }
    __syncthreads();
    float* pd = (float*)pool;            // [16*9][16] = 9216 B
    int*   pi = (int*)(pool + 9216);     // [16*9][16] = 9216 B
#pragma unroll
    for (int k = 0; k < 9; ++k) {
        pd[(chunk * 9 + k) * 16 + nl] = best[k];
        pi[(chunk * 9 + k) * 16 + nl] = bi[k];
    }
    __syncthreads();
    if (tid < 16) {
        int node = tid;
        float fb[9]; int fi[9];
#pragma unroll
        for (int k = 0; k < 9; ++k) { fb[k] = FLT_MAX; fi[k] = 0; }
        for (int c = 0; c < 16; ++c) {
            for (int k = 0; k < 9; ++k) {
                float d = pd[(c * 9 + k) * 16 + node];
                if (d >= fb[8]) break;   // chunk lists ascending
                int ci = pi[(c * 9 + k) * 16 + node];
                float cd = d;
#pragma unroll
                for (int j = 0; j < 9; ++j) {
                    if (cd < fb[j]) {
                        float td = fb[j]; fb[j] = cd; cd = td;
                        int ti = fi[j]; fi[j] = ci; ci = ti;
                    }
                }
            }
        }
        int gn = b * NPTS + blockIdx.x * 16 + node;
#pragma unroll
        for (int k = 0; k < 8; ++k) idx[(size_t)gn * 8 + k] = b * NPTS + fi[k];
        if (fb[8] - fb[7] <= KNN_EPS) {       // ambiguous 8/9 boundary -> exact redo
            int p = atomicAdd(fcount, 1);
            flist[p] = gn;
        }
    }
}

// ---------------- kNN pass 2: exact fp64 redo for flagged nodes (rare) ----------------
__global__ __launch_bounds__(256) void knn64_redo(const float* __restrict__ x, const int* __restrict__ flist,
                                                  const int* __restrict__ fcount, int* __restrict__ idx) {
    __shared__ double sd[2048];
    __shared__ int    si[2048];
    int cnt = *fcount;
    int tid = threadIdx.x;
    for (int it = blockIdx.x; it < cnt; it += gridDim.x) {
        int gn = flist[it];
        int b = gn >> 11, n = gn & 2047;
        const float* xb = x + (size_t)b * NPTS * 3;
        float n0 = xb[n * 3], n1 = xb[n * 3 + 1], n2 = xb[n * 3 + 2];
        double sqn = ((double)n0 * n0 + (double)n1 * n1) + (double)n2 * n2;
        double bd[8]; int bidx[8];
#pragma unroll
        for (int k = 0; k < 8; ++k) { bd[k] = DBL_MAX; bidx[k] = 0; }
        for (int j = 0; j < 8; ++j) {
            int m = tid * 8 + j;
            float c0 = xb[m * 3], c1 = xb[m * 3 + 1], c2 = xb[m * 3 + 2];
            double sqm = ((double)c0 * c0 + (double)c1 * c1) + (double)c2 * c2;
            double dot = ((double)n0 * c0 + (double)n1 * c1) + (double)n2 * c2;
            double d = (sqn + sqm) - 2.0 * dot;
            if (m == n) continue;
            if (d < bd[7]) {
                double cd = d; int ci = m;
#pragma unroll
                for (int q = 0; q < 8; ++q) {
                    if (cd < bd[q]) {
                        double td = bd[q]; bd[q] = cd; cd = td;
                        int ti = bidx[q]; bidx[q] = ci; ci = ti;
                    }
                }
            }
        }
#pragma unroll
        for (int k = 0; k < 8; ++k) { sd[tid * 8 + k] = bd[k]; si[tid * 8 + k] = bidx[k]; }
        __syncthreads();
        if (tid == 0) {
            double fb[8]; int fi[8];
#pragma unroll
            for (int k = 0; k < 8; ++k) { fb[k] = DBL_MAX; fi[k] = 0; }
            for (int t = 0; t < 256; ++t) {
                for (int k = 0; k < 8; ++k) {
                    double d = sd[t * 8 + k];
                    if (d >= fb[7]) break;
                    int ci = si[t * 8 + k];
                    double cd = d;
#pragma unroll
                    for (int q = 0; q < 8; ++q) {
                        if (cd < fb[q]) {
                            double td = fb[q]; fb[q] = cd; cd = td;
                            int ti = fi[q]; fi[q] = ci; ci = ti;
                        }
                    }
                }
            }
#pragma unroll
            for (int k = 0; k < 8; ++k) idx[(size_t)gn * 8 + k] = b * NPTS + fi[k];
        }
        __syncthreads();
    }
}

// ---------------- init MLP + LayerNorm -> bf16 feat ----------------
__global__ __launch_bounds__(256) void init_ln(const float* __restrict__ x, const float* __restrict__ W0,
                                               const float* __restrict__ b0, const float* __restrict__ g,
                                               const float* __restrict__ be, short* __restrict__ feat) {
    int t = blockIdx.x * 256 + threadIdx.x;
    int node = t >> 6, c = t & 63;
    const float* xp = x + (size_t)node * 3;
    float h = fmaf(xp[0], W0[c], fmaf(xp[1], W0[64 + c], fmaf(xp[2], W0[128 + c], b0[c])));
    h = lrelu(h);
    float s = h;
#pragma unroll
    for (int o = 32; o > 0; o >>= 1) s += __shfl_xor(s, o);
    float mu = s * (1.0f / 64.0f);
    float tt = h - mu;
    float q = tt * tt;
#pragma unroll
    for (int o = 32; o > 0; o >>= 1) q += __shfl_xor(q, o);
    float var = q * (1.0f / 64.0f);
    feat[t] = f2bf(tt * rsqrtf(var + 1e-5f) * g[c] + be[c]);
}

// ---------------- bf16 MFMA GEMM: C(MxN) = A(MxK) @ Bt(NxK)^T, 128x128 tile, BK=64 ----------------
__global__ __launch_bounds__(256) void gemm_mfma(const short* __restrict__ A, const short* __restrict__ Bt,
                                                 short* __restrict__ C, int N, int K,
                                                 const float* __restrict__ bias, int fuse_lrelu) {
    __shared__ __align__(16) char Asw[128 * 128];  // 128 rows x 128B, XOR-swizzled
    __shared__ __align__(16) char Bsw[128 * 128];
    int tid = threadIdx.x;
    int lane = tid & 63, wid = tid >> 6;
    int wm = wid >> 1, wn = wid & 1;
    int mBase = blockIdx.x * 128, nBase = blockIdx.y * 128;
    int lo = lane & 15, hi = lane >> 4;

    f32x4 acc[4][4];
#pragma unroll
    for (int i = 0; i < 4; ++i)
#pragma unroll
        for (int j = 0; j < 4; ++j) acc[i][j] = (f32x4){0.f, 0.f, 0.f, 0.f};

    int sr = tid >> 3;   // 0..31
    int sc = tid & 7;    // 16B chunk in row

    for (int k0 = 0; k0 < K; k0 += 64) {
        bf16x8 av[4], bv[4];
#pragma unroll
        for (int i = 0; i < 4; ++i) {
            int row = i * 32 + sr;
            av[i] = *(const bf16x8*)(A + (size_t)(mBase + row) * K + k0 + sc * 8);
            bv[i] = *(const bf16x8*)(Bt + (size_t)(nBase + row) * K + k0 + sc * 8);
        }
        __syncthreads();
#pragma unroll
        for (int i = 0; i < 4; ++i) {
            int row = i * 32 + sr;
            int off = row * 128 + ((sc * 16) ^ ((row & 7) << 4));
            *(bf16x8*)(Asw + off) = av[i];
            *(bf16x8*)(Bsw + off) = bv[i];
        }
        __syncthreads();
#pragma unroll
        for (int kk = 0; kk < 2; ++kk) {
            bf16x8 af[4], bfr[4];
            int kb = kk * 64 + hi * 16;
#pragma unroll
            for (int q = 0; q < 4; ++q) {
                int rowA = wm * 64 + q * 16 + lo;
                af[q] = *(const bf16x8*)(Asw + rowA * 128 + (kb ^ ((rowA & 7) << 4)));
                int rowB = wn * 64 + q * 16 + lo;
                bfr[q] = *(const bf16x8*)(Bsw + rowB * 128 + (kb ^ ((rowB & 7) << 4)));
            }
#pragma unroll
            for (int fm = 0; fm < 4; ++fm)
#pragma unroll
                for (int fn = 0; fn < 4; ++fn)
                    acc[fm][fn] = __builtin_amdgcn_mfma_f32_16x16x32_bf16(af[fm], bfr[fn], acc[fm][fn], 0, 0, 0);
        }
    }

    // C/D layout (HW-verified): col = lane&15, row = (lane>>4)*4 + reg
#pragma unroll
    for (int fm = 0; fm < 4; ++fm) {
        int m0 = mBase + wm * 64 + fm * 16 + hi * 4;
#pragma unroll
        for (int fn = 0; fn < 4; ++fn) {
            int n = nBase + wn * 64 + fn * 16 + lo;
            float bb = bias ? bias[n] : 0.0f;
#pragma unroll
            for (int rr = 0; rr < 4; ++rr) {
                float v = acc[fm][fn][rr] + bb;
                if (fuse_lrelu) v = lrelu(v);
                C[(size_t)(m0 + rr) * N + n] = f2bf(v);
            }
        }
    }
}

// ---------------- edge aggregate: x[n] = lrelu(U[n] - V[n] + bias[b] + max_k V[idx_k]) ----------------
__global__ __launch_bounds__(256) void edge_max(const short* __restrict__ UV, const int* __restrict__ idx,
                                                const float* __restrict__ bias, short* __restrict__ out,
                                                int F, int lf /* log2(F/8) */) {
    int gid = blockIdx.x * 256 + threadIdx.x;
    int n = gid >> lf;
    int f = (gid & ((F >> 3) - 1)) << 3;
    int b = n >> 11;
    int F2 = F << 1;
    const short* base = UV + (size_t)n * F2;
    bf16x8 u8 = *(const bf16x8*)(base + f);
    bf16x8 v8 = *(const bf16x8*)(base + F + f);
    const int* ip = idx + (size_t)n * 8;
    float mx[8];
#pragma unroll
    for (int j = 0; j < 8; ++j) mx[j] = -FLT_MAX;
#pragma unroll
    for (int k = 0; k < 8; ++k) {
        bf16x8 w8 = *(const bf16x8*)(UV + (size_t)ip[k] * F2 + F + f);
#pragma unroll
        for (int j = 0; j < 8; ++j) mx[j] = fmaxf(mx[j], b2f(w8[j]));
    }
    const float* bp = bias + (size_t)b * F + f;
    bf16x8 z;
#pragma unroll
    for (int j = 0; j < 8; ++j)
        z[j] = f2bf(lrelu(b2f(u8[j]) - b2f(v8[j]) + bp[j] + mx[j]));
    *(bf16x8*)(out + (size_t)n * F + f) = z;
}

// ---------------- final: out = x + hf @ Wf2 + bf2 ----------------
__global__ __launch_bounds__(256) void final_out(const short* __restrict__ hf, const float* __restrict__ Wf2,
                                                 const float* __restrict__ bf2, const float* __restrict__ x,
                                                 float* __restrict__ out) {
    int n = blockIdx.x * 256 + threadIdx.x;
    const short* h = hf + (size_t)n * 256;
    float s0 = bf2[0], s1 = bf2[1], s2 = bf2[2];
    for (int k8 = 0; k8 < 32; ++k8) {
        bf16x8 hv = *(const bf16x8*)(h + k8 * 8);
        const float* w = Wf2 + k8 * 24;
#pragma unroll
        for (int j = 0; j < 8; ++j) {
            float hh = b2f(hv[j]);
            s0 = fmaf(hh, w[j * 3 + 0], s0);
            s1 = fmaf(hh, w[j * 3 + 1], s1);
            s2 = fmaf(hh, w[j * 3 + 2], s2);
        }
    }
    out[n * 3 + 0] = x[n * 3 + 0] + s0;
    out[n * 3 + 1] = x[n * 3 + 1] + s1;
    out[n * 3 + 2] = x[n * 3 + 2] + s2;
}

extern "C" void kernel_launch(void* const* d_in, const int* in_sizes, int n_in,
                              void* d_out, int out_size, void* d_ws, size_t ws_size,
                              hipStream_t stream) {
    const float* x    = (const float*)d_in[0];
    const float* beta = (const float*)d_in[1];
    const float* ctxv = (const float*)d_in[2];
    const float* cond = (const float*)d_in[3];
    const float* W0   = (const float*)d_in[4];
    const float* b0   = (const float*)d_in[5];
    const float* ln_g = (const float*)d_in[6];
    const float* ln_b = (const float*)d_in[7];
    const float* W1   = (const float*)d_in[8];
    const float* b1   = (const float*)d_in[9];
    const float* W2   = (const float*)d_in[10];
    const float* b2   = (const float*)d_in[11];
    const float* W3   = (const float*)d_in[12];
    const float* b3   = (const float*)d_in[13];
    const float* Wf1  = (const float*)d_in[14];
    const float* bf1  = (const float*)d_in[15];
    const float* Wf2  = (const float*)d_in[16];
    const float* bf2  = (const float*)d_in[17];
    float* out = (float*)d_out;

    char* ws = (char*)d_ws;
    size_t off = 0;
    auto alloc = [&](size_t bytes) -> void* {
        void* p = ws + off;
        off += bytes;
        off = (off + 511) & ~(size_t)511;
        return p;
    };

    int*   idx    = (int*)alloc((size_t)M * 8 * 4);
    int*   fcount = (int*)alloc(4);
    int*   flist  = (int*)alloc((size_t)M * 4);
    float* ctx   = (float*)alloc((size_t)BATCH * CTXW * 4);
    float* bias1 = (float*)alloc((size_t)BATCH * 128 * 4);
    float* bias2 = (float*)alloc((size_t)BATCH * 256 * 4);
    float* bias3 = (float*)alloc((size_t)BATCH * 512 * 4);
    short* W1p   = (short*)alloc((size_t)256 * 64 * 2);
    short* W2p   = (short*)alloc((size_t)512 * 128 * 2);
    short* W3p   = (short*)alloc((size_t)1024 * 256 * 2);
    short* Wf1p  = (short*)alloc((size_t)256 * 512 * 2);
    short* R1    = (short*)alloc((size_t)M * 1024 * 2);  // feat0, later UV3
    short* R2    = (short*)alloc((size_t)M * 512 * 2);   // UV1, UV2, x3
    short* R3    = (short*)alloc((size_t)M * 256 * 2);   // x1, hf
    short* R4    = (short*)alloc((size_t)M * 256 * 2);   // x2

    short* feat0 = R1;
    short* UV1 = R2;  short* x1 = R3;
    short* UV2 = R2;  short* x2 = R4;
    short* UV3 = R1;  short* x3 = R2;
    short* hf  = R3;

    zero1<<<1, 1, 0, stream>>>(fcount);
    build_ctx<<<BATCH, 256, 0, stream>>>(beta, ctxv, cond, ctx);
    ctx_bias_all<<<dim3(14, BATCH), 256, 0, stream>>>(ctx, W1, b1, W2, b2, W3, b3, bias1, bias2, bias3);
    pack_all<<<(475136 + 255) / 256, 256, 0, stream>>>(W1, W2, W3, Wf1, W1p, W2p, W3p, Wf1p);

    knn32<<<dim3(NPTS / 16, BATCH), 256, 0, stream>>>(x, idx, flist, fcount);
    init_ln<<<M * 64 / 256, 256, 0, stream>>>(x, W0, b0, ln_g, ln_b, feat0);
    knn64_redo<<<256, 256, 0, stream>>>(x, flist, fcount, idx);

    gemm_mfma<<<dim3(M / 128, 2), 256, 0, stream>>>(feat0, W1p, UV1, 256, 64, nullptr, 0);
    edge_max<<<M * 16 / 256, 256, 0, stream>>>(UV1, idx, bias1, x1, 128, 4);

    gemm_mfma<<<dim3(M / 128, 4), 256, 0, stream>>>(x1, W2p, UV2, 512, 128, nullptr, 0);
    edge_max<<<M * 32 / 256, 256, 0, stream>>>(UV2, idx, bias2, x2, 256, 5);

    gemm_mfma<<<dim3(M / 128, 8), 256, 0, stream>>>(x2, W3p, UV3, 1024, 256, nullptr, 0);
    edge_max<<<M * 64 / 256, 256, 0, stream>>>(UV3, idx, bias3, x3, 512, 6);

    gemm_mfma<<<dim3(M / 128, 2), 256, 0, stream>>>(x3, Wf1p, hf, 256, 512, bf1, 1);

    final_out<<<M / 256, 256, 0, stream>>>(hf, Wf2, bf2, x, out);
}

// Round 5
// 582.985 us; speedup vs baseline: 1.0503x; 1.0503x over previous
//
#include <hip/hip_runtime.h>
#include <cfloat>

constexpr int BATCH = 8, NPTS = 2048;
constexpr int M = BATCH * NPTS;   // 16384 nodes
constexpr int CTXW = 515;
constexpr float KNN_EPS = 1e-3f;  // fp32 distance abs-error bound ~2e-5; 50x margin

typedef __attribute__((ext_vector_type(8))) short bf16x8;
typedef __attribute__((ext_vector_type(4))) float f32x4;

__device__ __forceinline__ float lrelu(float v) { return v > 0.0f ? v : 0.2f * v; }
__device__ __forceinline__ float b2f(short u) {
    return __uint_as_float(((unsigned int)(unsigned short)u) << 16);
}
__device__ __forceinline__ short f2bf(float f) {
    unsigned int u = __float_as_uint(f);
    return (short)((u + 0x7FFF + ((u >> 16) & 1)) >> 16);
}

__global__ void zero1(int* p) { *p = 0; }

// ---------------- ctx vector ----------------
__global__ void build_ctx(const float* __restrict__ beta, const float* __restrict__ ctxv,
                          const float* __restrict__ cond, float* __restrict__ ctx) {
    int b = blockIdx.x;
    float be = beta[b];
    for (int i = threadIdx.x; i < CTXW; i += blockDim.x) {
        float v;
        if (i == 0) v = be;
        else if (i == 1) v = sinf(be);
        else if (i == 2) v = cosf(be);
        else if (i < 259) v = ctxv[b * 256 + (i - 3)];
        else v = cond[b * 256 + (i - 259)];
        ctx[b * CTXW + i] = v;
    }
}

// fused: bias_ctx for layers 1..3; grid (14, BATCH)
__global__ __launch_bounds__(256) void ctx_bias_all(const float* __restrict__ ctx,
        const float* __restrict__ W1, const float* __restrict__ b1,
        const float* __restrict__ W2, const float* __restrict__ b2,
        const float* __restrict__ W3, const float* __restrict__ b3,
        float* __restrict__ bias1, float* __restrict__ bias2, float* __restrict__ bias3) {
    int b = blockIdx.y, blk = blockIdx.x;
    const float *W, *bv; float* out; int rowOff, F, fblk;
    if (blk < 2)      { W = W1; bv = b1; out = bias1; rowOff = 128; F = 128; fblk = blk; }
    else if (blk < 6) { W = W2; bv = b2; out = bias2; rowOff = 256; F = 256; fblk = blk - 2; }
    else              { W = W3; bv = b3; out = bias3; rowOff = 512; F = 512; fblk = blk - 6; }
    int fl = threadIdx.x >> 2, ks = threadIdx.x & 3;
    int f = fblk * 64 + fl;
    const float* c = ctx + b * CTXW;
    const float* w = W + (size_t)rowOff * F + f;
    float s = 0.f;
    for (int i = ks; i < CTXW; i += 4) s = fmaf(c[i], w[(size_t)i * F], s);
    s += __shfl_xor(s, 1);
    s += __shfl_xor(s, 2);
    if (ks == 0) out[(size_t)b * F + f] = s + bv[f];
}

// fused weight pack (transposed bf16): W1p(256x64) W2p(512x128) W3p(1024x256) Wf1p(256x512)
__global__ void pack_all(const float* __restrict__ W1, const float* __restrict__ W2,
                         const float* __restrict__ W3, const float* __restrict__ Wf1,
                         short* __restrict__ W1p, short* __restrict__ W2p,
                         short* __restrict__ W3p, short* __restrict__ Wf1p) {
    int gid = blockIdx.x * 256 + threadIdx.x;
    if (gid < 16384) {
        int j = gid >> 6, k = gid & 63;
        float v = (j < 128) ? W1[(size_t)k * 128 + j] : W1[(size_t)(64 + k) * 128 + (j - 128)];
        W1p[gid] = f2bf(v);
    } else if (gid < 81920) {
        int g = gid - 16384; int j = g >> 7, k = g & 127;
        float v = (j < 256) ? W2[(size_t)k * 256 + j] : W2[(size_t)(128 + k) * 256 + (j - 256)];
        W2p[g] = f2bf(v);
    } else if (gid < 344064) {
        int g = gid - 81920; int j = g >> 8, k = g & 255;
        float v = (j < 512) ? W3[(size_t)k * 512 + j] : W3[(size_t)(256 + k) * 512 + (j - 512)];
        W3p[g] = f2bf(v);
    } else if (gid < 475136) {
        int g = gid - 344064; int f = g >> 9, k = g & 511;
        Wf1p[g] = f2bf(Wf1[(size_t)k * 256 + f]);
    }
}

// ---------------- kNN pass 1: fp32 scan, top-9, gap-flag ambiguous nodes ----------------
// Block: 16 nodes x 16 chunks. launch_bounds(256,1): lift VGPR cap so top-k arrays
// stay in registers (44-VGPR cap spilled them to scratch -> ~L2 latency per scan iter).
__global__ __launch_bounds__(256, 1) void knn32(const float* __restrict__ x, int* __restrict__ idx,
                                                int* __restrict__ flist, int* __restrict__ fcount) {
    __shared__ __align__(16) char pool[32768];
    float4* xs4 = (float4*)pool;              // 2048*16 = 32768 B
    int b = blockIdx.y;
    const float* xb = x + (size_t)b * NPTS * 3;
    int tid = threadIdx.x;
    for (int i = tid; i < NPTS; i += 256) {
        float a0 = xb[i * 3], a1 = xb[i * 3 + 1], a2 = xb[i * 3 + 2];
        float sq = (a0 * a0 + a1 * a1) + a2 * a2;
        xs4[i] = make_float4(a0, a1, a2, sq);
    }
    __syncthreads();

    int nl = tid & 15;            // node within block
    int chunk = tid >> 4;         // candidate chunk 0..15
    int n = blockIdx.x * 16 + nl;
    float4 me = xs4[n];
    float sqn = me.w;
    float best[9];
    int bi[9];
#pragma unroll
    for (int k = 0; k < 9; ++k) { best[k] = FLT_MAX; bi[k] = 0; }
    int mbase = chunk * 128;
    int nloc = n - mbase;         // in [0,128) only if self in this chunk
    for (int i = 0; i < 128; ++i) {
        int ii = (i + chunk * 2) & 127;   // stagger: de-conflict banks across chunk groups
        int m = mbase + ii;
        float4 c = xs4[m];
        float dot = fmaf(me.x, c.x, fmaf(me.y, c.y, me.z * c.z));
        float d = fmaf(-2.0f, dot, sqn + c.w);
        if (ii != nloc && d < best[8]) {
            float cd = d; int ci = m;
#pragma unroll
            for (int j = 0; j < 9; ++j) {
                if (cd < best[j]) {
                    float td = best[j]; best[j] = cd; cd = td;
                    int ti = bi[j]; bi[j] = ci; ci = ti;
                }
            }
        }
    }
    __syncthreads();
    float* pd = (float*)pool;            // [16*9][16] = 9216 B
    int*   pi = (int*)(pool + 9216);     // [16*9][16] = 9216 B
#pragma unroll
    for (int k = 0; k < 9; ++k) {
        pd[(chunk * 9 + k) * 16 + nl] = best[k];
        pi[(chunk * 9 + k) * 16 + nl] = bi[k];
    }
    __syncthreads();
    if (tid < 16) {
        int node = tid;
        float fb[9]; int fi[9];
#pragma unroll
        for (int k = 0; k < 9; ++k) { fb[k] = FLT_MAX; fi[k] = 0; }
        for (int c = 0; c < 16; ++c) {
            for (int k = 0; k < 9; ++k) {
                float d = pd[(c * 9 + k) * 16 + node];
                if (d >= fb[8]) break;   // chunk lists ascending
                int ci = pi[(c * 9 + k) * 16 + node];
                float cd = d;
#pragma unroll
                for (int j = 0; j < 9; ++j) {
                    if (cd < fb[j]) {
                        float td = fb[j]; fb[j] = cd; cd = td;
                        int ti = fi[j]; fi[j] = ci; ci = ti;
                    }
                }
            }
        }
        int gn = b * NPTS + blockIdx.x * 16 + node;
#pragma unroll
        for (int k = 0; k < 8; ++k) idx[(size_t)gn * 8 + k] = b * NPTS + fi[k];
        if (fb[8] - fb[7] <= KNN_EPS) {       // ambiguous 8/9 boundary -> exact redo
            int p = atomicAdd(fcount, 1);
            flist[p] = gn;
        }
    }
}

// ---------------- kNN pass 2: exact fp64 redo for flagged nodes ----------------
// Two-level merge (16-way then final) removes the 2048-entry serial chain;
// launch_bounds(256,1) keeps the fp64 top-k arrays in registers.
__global__ __launch_bounds__(256, 1) void knn64_redo(const float* __restrict__ x, const int* __restrict__ flist,
                                                     const int* __restrict__ fcount, int* __restrict__ idx) {
    __shared__ double sd[2048];
    __shared__ int    si[2048];
    __shared__ double s2d[128];
    __shared__ int    s2i[128];
    int cnt = *fcount;
    int tid = threadIdx.x;
    for (int it = blockIdx.x; it < cnt; it += gridDim.x) {
        int gn = flist[it];
        int b = gn >> 11, n = gn & 2047;
        const float* xb = x + (size_t)b * NPTS * 3;
        float n0 = xb[n * 3], n1 = xb[n * 3 + 1], n2 = xb[n * 3 + 2];
        double sqn = ((double)n0 * n0 + (double)n1 * n1) + (double)n2 * n2;
        double bd[8]; int bidx[8];
#pragma unroll
        for (int k = 0; k < 8; ++k) { bd[k] = DBL_MAX; bidx[k] = 0; }
        for (int j = 0; j < 8; ++j) {
            int m = tid * 8 + j;           // ascending index order per thread (stable ties)
            float c0 = xb[m * 3], c1 = xb[m * 3 + 1], c2 = xb[m * 3 + 2];
            double sqm = ((double)c0 * c0 + (double)c1 * c1) + (double)c2 * c2;
            double dot = ((double)n0 * c0 + (double)n1 * c1) + (double)n2 * c2;
            double d = (sqn + sqm) - 2.0 * dot;
            if (m == n) continue;
            if (d < bd[7]) {
                double cd = d; int ci = m;
#pragma unroll
                for (int q = 0; q < 8; ++q) {
                    if (cd < bd[q]) {
                        double td = bd[q]; bd[q] = cd; cd = td;
                        int ti = bidx[q]; bidx[q] = ci; ci = ti;
                    }
                }
            }
        }
#pragma unroll
        for (int k = 0; k < 8; ++k) { sd[tid * 8 + k] = bd[k]; si[tid * 8 + k] = bidx[k]; }
        __syncthreads();
        if (tid < 16) {
            double fb[8]; int fi[8];
#pragma unroll
            for (int k = 0; k < 8; ++k) { fb[k] = DBL_MAX; fi[k] = 0; }
            for (int t = tid * 16; t < tid * 16 + 16; ++t) {   // ascending thread order (stable)
                for (int k = 0; k < 8; ++k) {
                    double d = sd[t * 8 + k];
                    if (d >= fb[7]) break;                     // per-thread lists ascending
                    int ci = si[t * 8 + k];
                    double cd = d;
#pragma unroll
                    for (int q = 0; q < 8; ++q) {
                        if (cd < fb[q]) {
                            double td = fb[q]; fb[q] = cd; cd = td;
                            int ti = fi[q]; fi[q] = ci; ci = ti;
                        }
                    }
                }
            }
#pragma unroll
            for (int k = 0; k < 8; ++k) { s2d[tid * 8 + k] = fb[k]; s2i[tid * 8 + k] = fi[k]; }
        }
        __syncthreads();
        if (tid == 0) {
            double fb[8]; int fi[8];
#pragma unroll
            for (int k = 0; k < 8; ++k) { fb[k] = DBL_MAX; fi[k] = 0; }
            for (int t = 0; t < 16; ++t) {
                for (int k = 0; k < 8; ++k) {
                    double d = s2d[t * 8 + k];
                    if (d >= fb[7]) break;
                    int ci = s2i[t * 8 + k];
                    double cd = d;
#pragma unroll
                    for (int q = 0; q < 8; ++q) {
                        if (cd < fb[q]) {
                            double td = fb[q]; fb[q] = cd; cd = td;
                            int ti = fi[q]; fi[q] = ci; ci = ti;
                        }
                    }
                }
            }
#pragma unroll
            for (int k = 0; k < 8; ++k) idx[(size_t)gn * 8 + k] = b * NPTS + fi[k];
        }
        __syncthreads();
    }
}

// ---------------- init MLP + LayerNorm -> bf16 feat ----------------
__global__ __launch_bounds__(256) void init_ln(const float* __restrict__ x, const float* __restrict__ W0,
                                               const float* __restrict__ b0, const float* __restrict__ g,
                                               const float* __restrict__ be, short* __restrict__ feat) {
    int t = blockIdx.x * 256 + threadIdx.x;
    int node = t >> 6, c = t & 63;
    const float* xp = x + (size_t)node * 3;
    float h = fmaf(xp[0], W0[c], fmaf(xp[1], W0[64 + c], fmaf(xp[2], W0[128 + c], b0[c])));
    h = lrelu(h);
    float s = h;
#pragma unroll
    for (int o = 32; o > 0; o >>= 1) s += __shfl_xor(s, o);
    float mu = s * (1.0f / 64.0f);
    float tt = h - mu;
    float q = tt * tt;
#pragma unroll
    for (int o = 32; o > 0; o >>= 1) q += __shfl_xor(q, o);
    float var = q * (1.0f / 64.0f);
    feat[t] = f2bf(tt * rsqrtf(var + 1e-5f) * g[c] + be[c]);
}

// ---------------- bf16 MFMA GEMM: C(MxN) = A(MxK) @ Bt(NxK)^T, 128x128 tile, BK=64 ----------------
__global__ __launch_bounds__(256) void gemm_mfma(const short* __restrict__ A, const short* __restrict__ Bt,
                                                 short* __restrict__ C, int N, int K,
                                                 const float* __restrict__ bias, int fuse_lrelu) {
    __shared__ __align__(16) char Asw[128 * 128];  // 128 rows x 128B, XOR-swizzled
    __shared__ __align__(16) char Bsw[128 * 128];
    int tid = threadIdx.x;
    int lane = tid & 63, wid = tid >> 6;
    int wm = wid >> 1, wn = wid & 1;
    int mBase = blockIdx.x * 128, nBase = blockIdx.y * 128;
    int lo = lane & 15, hi = lane >> 4;

    f32x4 acc[4][4];
#pragma unroll
    for (int i = 0; i < 4; ++i)
#pragma unroll
        for (int j = 0; j < 4; ++j) acc[i][j] = (f32x4){0.f, 0.f, 0.f, 0.f};

    int sr = tid >> 3;   // 0..31
    int sc = tid & 7;    // 16B chunk in row

    for (int k0 = 0; k0 < K; k0 += 64) {
        bf16x8 av[4], bv[4];
#pragma unroll
        for (int i = 0; i < 4; ++i) {
            int row = i * 32 + sr;
            av[i] = *(const bf16x8*)(A + (size_t)(mBase + row) * K + k0 + sc * 8);
            bv[i] = *(const bf16x8*)(Bt + (size_t)(nBase + row) * K + k0 + sc * 8);
        }
        __syncthreads();
#pragma unroll
        for (int i = 0; i < 4; ++i) {
            int row = i * 32 + sr;
            int off = row * 128 + ((sc * 16) ^ ((row & 7) << 4));
            *(bf16x8*)(Asw + off) = av[i];
            *(bf16x8*)(Bsw + off) = bv[i];
        }
        __syncthreads();
#pragma unroll
        for (int kk = 0; kk < 2; ++kk) {
            bf16x8 af[4], bfr[4];
            int kb = kk * 64 + hi * 16;
#pragma unroll
            for (int q = 0; q < 4; ++q) {
                int rowA = wm * 64 + q * 16 + lo;
                af[q] = *(const bf16x8*)(Asw + rowA * 128 + (kb ^ ((rowA & 7) << 4)));
                int rowB = wn * 64 + q * 16 + lo;
                bfr[q] = *(const bf16x8*)(Bsw + rowB * 128 + (kb ^ ((rowB & 7) << 4)));
            }
#pragma unroll
            for (int fm = 0; fm < 4; ++fm)
#pragma unroll
                for (int fn = 0; fn < 4; ++fn)
                    acc[fm][fn] = __builtin_amdgcn_mfma_f32_16x16x32_bf16(af[fm], bfr[fn], acc[fm][fn], 0, 0, 0);
        }
    }

    // C/D layout (HW-verified): col = lane&15, row = (lane>>4)*4 + reg
#pragma unroll
    for (int fm = 0; fm < 4; ++fm) {
        int m0 = mBase + wm * 64 + fm * 16 + hi * 4;
#pragma unroll
        for (int fn = 0; fn < 4; ++fn) {
            int n = nBase + wn * 64 + fn * 16 + lo;
            float bb = bias ? bias[n] : 0.0f;
#pragma unroll
            for (int rr = 0; rr < 4; ++rr) {
                float v = acc[fm][fn][rr] + bb;
                if (fuse_lrelu) v = lrelu(v);
                C[(size_t)(m0 + rr) * N + n] = f2bf(v);
            }
        }
    }
}

// ---------------- edge aggregate: x[n] = lrelu(U[n] - V[n] + bias[b] + max_k V[idx_k]) ----------------
__global__ __launch_bounds__(256) void edge_max(const short* __restrict__ UV, const int* __restrict__ idx,
                                                const float* __restrict__ bias, short* __restrict__ out,
                                                int F, int lf /* log2(F/8) */) {
    int gid = blockIdx.x * 256 + threadIdx.x;
    int n = gid >> lf;
    int f = (gid & ((F >> 3) - 1)) << 3;
    int b = n >> 11;
    int F2 = F << 1;
    const short* base = UV + (size_t)n * F2;
    bf16x8 u8 = *(const bf16x8*)(base + f);
    bf16x8 v8 = *(const bf16x8*)(base + F + f);
    const int* ip = idx + (size_t)n * 8;
    float mx[8];
#pragma unroll
    for (int j = 0; j < 8; ++j) mx[j] = -FLT_MAX;
#pragma unroll
    for (int k = 0; k < 8; ++k) {
        bf16x8 w8 = *(const bf16x8*)(UV + (size_t)ip[k] * F2 + F + f);
#pragma unroll
        for (int j = 0; j < 8; ++j) mx[j] = fmaxf(mx[j], b2f(w8[j]));
    }
    const float* bp = bias + (size_t)b * F + f;
    bf16x8 z;
#pragma unroll
    for (int j = 0; j < 8; ++j)
        z[j] = f2bf(lrelu(b2f(u8[j]) - b2f(v8[j]) + bp[j] + mx[j]));
    *(bf16x8*)(out + (size_t)n * F + f) = z;
}

// ---------------- final: out = x + hf @ Wf2 + bf2 ----------------
__global__ __launch_bounds__(256) void final_out(const short* __restrict__ hf, const float* __restrict__ Wf2,
                                                 const float* __restrict__ bf2, const float* __restrict__ x,
                                                 float* __restrict__ out) {
    int n = blockIdx.x * 256 + threadIdx.x;
    const short* h = hf + (size_t)n * 256;
    float s0 = bf2[0], s1 = bf2[1], s2 = bf2[2];
    for (int k8 = 0; k8 < 32; ++k8) {
        bf16x8 hv = *(const bf16x8*)(h + k8 * 8);
        const float* w = Wf2 + k8 * 24;
#pragma unroll
        for (int j = 0; j < 8; ++j) {
            float hh = b2f(hv[j]);
            s0 = fmaf(hh, w[j * 3 + 0], s0);
            s1 = fmaf(hh, w[j * 3 + 1], s1);
            s2 = fmaf(hh, w[j * 3 + 2], s2);
        }
    }
    out[n * 3 + 0] = x[n * 3 + 0] + s0;
    out[n * 3 + 1] = x[n * 3 + 1] + s1;
    out[n * 3 + 2] = x[n * 3 + 2] + s2;
}

extern "C" void kernel_launch(void* const* d_in, const int* in_sizes, int n_in,
                              void* d_out, int out_size, void* d_ws, size_t ws_size,
                              hipStream_t stream) {
    const float* x    = (const float*)d_in[0];
    const float* beta = (const float*)d_in[1];
    const float* ctxv = (const float*)d_in[2];
    const float* cond = (const float*)d_in[3];
    const float* W0   = (const float*)d_in[4];
    const float* b0   = (const float*)d_in[5];
    const float* ln_g = (const float*)d_in[6];
    const float* ln_b = (const float*)d_in[7];
    const float* W1   = (const float*)d_in[8];
    const float* b1   = (const float*)d_in[9];
    const float* W2   = (const float*)d_in[10];
    const float* b2   = (const float*)d_in[11];
    const float* W3   = (const float*)d_in[12];
    const float* b3   = (const float*)d_in[13];
    const float* Wf1  = (const float*)d_in[14];
    const float* bf1  = (const float*)d_in[15];
    const float* Wf2  = (const float*)d_in[16];
    const float* bf2  = (const float*)d_in[17];
    float* out = (float*)d_out;

    char* ws = (char*)d_ws;
    size_t off = 0;
    auto alloc = [&](size_t bytes) -> void* {
        void* p = ws + off;
        off += bytes;
        off = (off + 511) & ~(size_t)511;
        return p;
    };

    int*   idx    = (int*)alloc((size_t)M * 8 * 4);
    int*   fcount = (int*)alloc(4);
    int*   flist  = (int*)alloc((size_t)M * 4);
    float* ctx   = (float*)alloc((size_t)BATCH * CTXW * 4);
    float* bias1 = (float*)alloc((size_t)BATCH * 128 * 4);
    float* bias2 = (float*)alloc((size_t)BATCH * 256 * 4);
    float* bias3 = (float*)alloc((size_t)BATCH * 512 * 4);
    short* W1p   = (short*)alloc((size_t)256 * 64 * 2);
    short* W2p   = (short*)alloc((size_t)512 * 128 * 2);
    short* W3p   = (short*)alloc((size_t)1024 * 256 * 2);
    short* Wf1p  = (short*)alloc((size_t)256 * 512 * 2);
    short* R1    = (short*)alloc((size_t)M * 1024 * 2);  // feat0, later UV3
    short* R2    = (short*)alloc((size_t)M * 512 * 2);   // UV1, UV2, x3
    short* R3    = (short*)alloc((size_t)M * 256 * 2);   // x1, hf
    short* R4    = (short*)alloc((size_t)M * 256 * 2);   // x2

    short* feat0 = R1;
    short* UV1 = R2;  short* x1 = R3;
    short* UV2 = R2;  short* x2 = R4;
    short* UV3 = R1;  short* x3 = R2;
    short* hf  = R3;

    zero1<<<1, 1, 0, stream>>>(fcount);
    build_ctx<<<BATCH, 256, 0, stream>>>(beta, ctxv, cond, ctx);
    ctx_bias_all<<<dim3(14, BATCH), 256, 0, stream>>>(ctx, W1, b1, W2, b2, W3, b3, bias1, bias2, bias3);
    pack_all<<<(475136 + 255) / 256, 256, 0, stream>>>(W1, W2, W3, Wf1, W1p, W2p, W3p, Wf1p);

    knn32<<<dim3(NPTS / 16, BATCH), 256, 0, stream>>>(x, idx, flist, fcount);
    init_ln<<<M * 64 / 256, 256, 0, stream>>>(x, W0, b0, ln_g, ln_b, feat0);
    knn64_redo<<<256, 256, 0, stream>>>(x, flist, fcount, idx);

    gemm_mfma<<<dim3(M / 128, 2), 256, 0, stream>>>(feat0, W1p, UV1, 256, 64, nullptr, 0);
    edge_max<<<M * 16 / 256, 256, 0, stream>>>(UV1, idx, bias1, x1, 128, 4);

    gemm_mfma<<<dim3(M / 128, 4), 256, 0, stream>>>(x1, W2p, UV2, 512, 128, nullptr, 0);
    edge_max<<<M * 32 / 256, 256, 0, stream>>>(UV2, idx, bias2, x2, 256, 5);

    gemm_mfma<<<dim3(M / 128, 8), 256, 0, stream>>>(x2, W3p, UV3, 1024, 256, nullptr, 0);
    edge_max<<<M * 64 / 256, 256, 0, stream>>>(UV3, idx, bias3, x3, 512, 6);

    gemm_mfma<<<dim3(M / 128, 2), 256, 0, stream>>>(x3, Wf1p, hf, 256, 512, bf1, 1);

    final_out<<<M / 256, 256, 0, stream>>>(hf, Wf2, bf2, x, out);
}

// Round 6
// 261.346 us; speedup vs baseline: 2.3430x; 2.2307x over previous
//
#include <hip/hip_runtime.h>
#include <cfloat>

constexpr int BATCH = 8, NPTS = 2048;
constexpr int M = BATCH * NPTS;   // 16384 nodes
constexpr int CTXW = 515;

typedef __attribute__((ext_vector_type(8))) short bf16x8;
typedef __attribute__((ext_vector_type(4))) float f32x4;

__device__ __forceinline__ float lrelu(float v) { return v > 0.0f ? v : 0.2f * v; }
__device__ __forceinline__ float b2f(short u) {
    return __uint_as_float(((unsigned int)(unsigned short)u) << 16);
}
__device__ __forceinline__ short f2bf(float f) {
    unsigned int u = __float_as_uint(f);
    return (short)((u + 0x7FFF + ((u >> 16) & 1)) >> 16);
}

__global__ void zero1(int* p) { *p = 0; }

// ---------------- ctx vector ----------------
__global__ void build_ctx(const float* __restrict__ beta, const float* __restrict__ ctxv,
                          const float* __restrict__ cond, float* __restrict__ ctx) {
    int b = blockIdx.x;
    float be = beta[b];
    for (int i = threadIdx.x; i < CTXW; i += blockDim.x) {
        float v;
        if (i == 0) v = be;
        else if (i == 1) v = sinf(be);
        else if (i == 2) v = cosf(be);
        else if (i < 259) v = ctxv[b * 256 + (i - 3)];
        else v = cond[b * 256 + (i - 259)];
        ctx[b * CTXW + i] = v;
    }
}

// fused: bias_ctx for layers 1..3; grid (14, BATCH)
__global__ __launch_bounds__(256) void ctx_bias_all(const float* __restrict__ ctx,
        const float* __restrict__ W1, const float* __restrict__ b1,
        const float* __restrict__ W2, const float* __restrict__ b2,
        const float* __restrict__ W3, const float* __restrict__ b3,
        float* __restrict__ bias1, float* __restrict__ bias2, float* __restrict__ bias3) {
    int b = blockIdx.y, blk = blockIdx.x;
    const float *W, *bv; float* out; int rowOff, F, fblk;
    if (blk < 2)      { W = W1; bv = b1; out = bias1; rowOff = 128; F = 128; fblk = blk; }
    else if (blk < 6) { W = W2; bv = b2; out = bias2; rowOff = 256; F = 256; fblk = blk - 2; }
    else              { W = W3; bv = b3; out = bias3; rowOff = 512; F = 512; fblk = blk - 6; }
    int fl = threadIdx.x >> 2, ks = threadIdx.x & 3;
    int f = fblk * 64 + fl;
    const float* c = ctx + b * CTXW;
    const float* w = W + (size_t)rowOff * F + f;
    float s = 0.f;
    for (int i = ks; i < CTXW; i += 4) s = fmaf(c[i], w[(size_t)i * F], s);
    s += __shfl_xor(s, 1);
    s += __shfl_xor(s, 2);
    if (ks == 0) out[(size_t)b * F + f] = s + bv[f];
}

// fused weight pack (transposed bf16): W1p(256x64) W2p(512x128) W3p(1024x256) Wf1p(256x512)
__global__ void pack_all(const float* __restrict__ W1, const float* __restrict__ W2,
                         const float* __restrict__ W3, const float* __restrict__ Wf1,
                         short* __restrict__ W1p, short* __restrict__ W2p,
                         short* __restrict__ W3p, short* __restrict__ Wf1p) {
    int gid = blockIdx.x * 256 + threadIdx.x;
    if (gid < 16384) {
        int j = gid >> 6, k = gid & 63;
        float v = (j < 128) ? W1[(size_t)k * 128 + j] : W1[(size_t)(64 + k) * 128 + (j - 128)];
        W1p[gid] = f2bf(v);
    } else if (gid < 81920) {
        int g = gid - 16384; int j = g >> 7, k = g & 127;
        float v = (j < 256) ? W2[(size_t)k * 256 + j] : W2[(size_t)(128 + k) * 256 + (j - 256)];
        W2p[g] = f2bf(v);
    } else if (gid < 344064) {
        int g = gid - 81920; int j = g >> 8, k = g & 255;
        float v = (j < 512) ? W3[(size_t)k * 512 + j] : W3[(size_t)(256 + k) * 512 + (j - 512)];
        W3p[g] = f2bf(v);
    } else if (gid < 475136) {
        int g = gid - 344064; int f = g >> 9, k = g & 511;
        Wf1p[g] = f2bf(Wf1[(size_t)k * 256 + f]);
    }
}

// ---------------- kNN: one wave per node, branch-free 9x min-extraction ----------------
// Lane l owns candidates {j*64+l}. Distances computed ONCE in diff-form (rel err ~6e-7,
// d>=0 so raw float bits are uint-sortable). Selection = 9 passes of register scan +
// shfl butterfly (index tie-break) + cndmask exclusion. No data-dependent branches.
__global__ __launch_bounds__(256, 1) void knn_sel(const float* __restrict__ x, int* __restrict__ idx,
                                                  int* __restrict__ flist, int* __restrict__ fcount) {
    __shared__ float4 xs4[NPTS];  // 32768 B
    int b = blockIdx.y;
    const float* xb = x + (size_t)b * NPTS * 3;
    int tid = threadIdx.x;
    for (int i = tid; i < NPTS; i += 256)
        xs4[i] = make_float4(xb[i * 3], xb[i * 3 + 1], xb[i * 3 + 2], 0.f);
    __syncthreads();

    int w = tid >> 6, l = tid & 63;
    int n = blockIdx.x * 4 + w;
    float4 me = xs4[n];
    unsigned key[32];
    int selfrel = n - l;              // candidate j*64+l == n  <=>  j*64 == selfrel
#pragma unroll
    for (int j = 0; j < 32; ++j) {
        float4 c = xs4[j * 64 + l];
        float dx = me.x - c.x, dy = me.y - c.y, dz = me.z - c.z;
        float d = fmaf(dx, dx, fmaf(dy, dy, dz * dz));
        unsigned k = __float_as_uint(d);
        key[j] = (j * 64 == selfrel) ? 0xFFFFFFFFu : k;
    }

    int gn = b * NPTS + n;
    unsigned k8 = 0, k9 = 0;
    for (int p = 0; p < 9; ++p) {
        unsigned bk = 0xFFFFFFFFu;
        int bidx = 0x7FFFFFFF;
#pragma unroll
        for (int j = 0; j < 32; ++j) {      // ascending j => stable (lowest index wins ties)
            bool t = key[j] < bk;
            bk = t ? key[j] : bk;
            bidx = t ? j * 64 + l : bidx;
        }
#pragma unroll
        for (int off = 32; off > 0; off >>= 1) {
            unsigned ok = __shfl_xor(bk, off);
            int oi = __shfl_xor(bidx, off);
            bool t = (ok < bk) || (ok == bk && oi < bidx);
            bk = t ? ok : bk;
            bidx = t ? oi : bidx;
        }
        int rel = bidx - l;                 // exclude winner (its owner lane, slot bidx>>6)
#pragma unroll
        for (int j = 0; j < 32; ++j)
            if (j * 64 == rel) key[j] = 0xFFFFFFFFu;
        if (p < 8) { if (l == p) idx[(size_t)gn * 8 + p] = b * NPTS + bidx; }
        if (p == 7) k8 = bk;
        if (p == 8) k9 = bk;
    }
    if (l == 0) {
        float d8 = __uint_as_float(k8), d9 = __uint_as_float(k9);
        float eps = 2e-5f * fmaxf(d9, 1.0f);   // >=30x the fp32 diff-form error bound
        if (d9 - d8 <= eps) {
            int pp = atomicAdd(fcount, 1);
            flist[pp] = gn;
        }
    }
}

// ---------------- kNN pass 2: exact fp64 redo for flagged nodes (rare) ----------------
__global__ __launch_bounds__(256, 1) void knn64_redo(const float* __restrict__ x, const int* __restrict__ flist,
                                                     const int* __restrict__ fcount, int* __restrict__ idx) {
    __shared__ double sd[2048];
    __shared__ int    si[2048];
    __shared__ double s2d[128];
    __shared__ int    s2i[128];
    int cnt = *fcount;
    int tid = threadIdx.x;
    for (int it = blockIdx.x; it < cnt; it += gridDim.x) {
        int gn = flist[it];
        int b = gn >> 11, n = gn & 2047;
        const float* xb = x + (size_t)b * NPTS * 3;
        float n0 = xb[n * 3], n1 = xb[n * 3 + 1], n2 = xb[n * 3 + 2];
        double sqn = ((double)n0 * n0 + (double)n1 * n1) + (double)n2 * n2;
        double bd[8]; int bidx[8];
#pragma unroll
        for (int k = 0; k < 8; ++k) { bd[k] = DBL_MAX; bidx[k] = 0; }
        for (int j = 0; j < 8; ++j) {
            int m = tid * 8 + j;           // ascending index order per thread (stable ties)
            float c0 = xb[m * 3], c1 = xb[m * 3 + 1], c2 = xb[m * 3 + 2];
            double sqm = ((double)c0 * c0 + (double)c1 * c1) + (double)c2 * c2;
            double dot = ((double)n0 * c0 + (double)n1 * c1) + (double)n2 * c2;
            double d = (sqn + sqm) - 2.0 * dot;
            if (m == n) continue;
            if (d < bd[7]) {
                double cd = d; int ci = m;
#pragma unroll
                for (int q = 0; q < 8; ++q) {
                    if (cd < bd[q]) {
                        double td = bd[q]; bd[q] = cd; cd = td;
                        int ti = bidx[q]; bidx[q] = ci; ci = ti;
                    }
                }
            }
        }
#pragma unroll
        for (int k = 0; k < 8; ++k) { sd[tid * 8 + k] = bd[k]; si[tid * 8 + k] = bidx[k]; }
        __syncthreads();
        if (tid < 16) {
            double fb[8]; int fi[8];
#pragma unroll
            for (int k = 0; k < 8; ++k) { fb[k] = DBL_MAX; fi[k] = 0; }
            for (int t = tid * 16; t < tid * 16 + 16; ++t) {
                for (int k = 0; k < 8; ++k) {
                    double d = sd[t * 8 + k];
                    if (d >= fb[7]) break;
                    int ci = si[t * 8 + k];
                    double cd = d;
#pragma unroll
                    for (int q = 0; q < 8; ++q) {
                        if (cd < fb[q]) {
                            double td = fb[q]; fb[q] = cd; cd = td;
                            int ti = fi[q]; fi[q] = ci; ci = ti;
                        }
                    }
                }
            }
#pragma unroll
            for (int k = 0; k < 8; ++k) { s2d[tid * 8 + k] = fb[k]; s2i[tid * 8 + k] = fi[k]; }
        }
        __syncthreads();
        if (tid == 0) {
            double fb[8]; int fi[8];
#pragma unroll
            for (int k = 0; k < 8; ++k) { fb[k] = DBL_MAX; fi[k] = 0; }
            for (int t = 0; t < 16; ++t) {
                for (int k = 0; k < 8; ++k) {
                    double d = s2d[t * 8 + k];
                    if (d >= fb[7]) break;
                    int ci = s2i[t * 8 + k];
                    double cd = d;
#pragma unroll
                    for (int q = 0; q < 8; ++q) {
                        if (cd < fb[q]) {
                            double td = fb[q]; fb[q] = cd; cd = td;
                            int ti = fi[q]; fi[q] = ci; ci = ti;
                        }
                    }
                }
            }
#pragma unroll
            for (int k = 0; k < 8; ++k) idx[(size_t)gn * 8 + k] = b * NPTS + fi[k];
        }
        __syncthreads();
    }
}

// ---------------- init MLP + LayerNorm -> bf16 feat ----------------
__global__ __launch_bounds__(256) void init_ln(const float* __restrict__ x, const float* __restrict__ W0,
                                               const float* __restrict__ b0, const float* __restrict__ g,
                                               const float* __restrict__ be, short* __restrict__ feat) {
    int t = blockIdx.x * 256 + threadIdx.x;
    int node = t >> 6, c = t & 63;
    const float* xp = x + (size_t)node * 3;
    float h = fmaf(xp[0], W0[c], fmaf(xp[1], W0[64 + c], fmaf(xp[2], W0[128 + c], b0[c])));
    h = lrelu(h);
    float s = h;
#pragma unroll
    for (int o = 32; o > 0; o >>= 1) s += __shfl_xor(s, o);
    float mu = s * (1.0f / 64.0f);
    float tt = h - mu;
    float q = tt * tt;
#pragma unroll
    for (int o = 32; o > 0; o >>= 1) q += __shfl_xor(q, o);
    float var = q * (1.0f / 64.0f);
    feat[t] = f2bf(tt * rsqrtf(var + 1e-5f) * g[c] + be[c]);
}

// ---------------- bf16 MFMA GEMM: C(MxN) = A(MxK) @ Bt(NxK)^T, 128x128 tile, BK=64 ----------------
__global__ __launch_bounds__(256) void gemm_mfma(const short* __restrict__ A, const short* __restrict__ Bt,
                                                 short* __restrict__ C, int N, int K,
                                                 const float* __restrict__ bias, int fuse_lrelu) {
    __shared__ __align__(16) char Asw[128 * 128];  // 128 rows x 128B, XOR-swizzled
    __shared__ __align__(16) char Bsw[128 * 128];
    int tid = threadIdx.x;
    int lane = tid & 63, wid = tid >> 6;
    int wm = wid >> 1, wn = wid & 1;
    int mBase = blockIdx.x * 128, nBase = blockIdx.y * 128;
    int lo = lane & 15, hi = lane >> 4;

    f32x4 acc[4][4];
#pragma unroll
    for (int i = 0; i < 4; ++i)
#pragma unroll
        for (int j = 0; j < 4; ++j) acc[i][j] = (f32x4){0.f, 0.f, 0.f, 0.f};

    int sr = tid >> 3;   // 0..31
    int sc = tid & 7;    // 16B chunk in row

    for (int k0 = 0; k0 < K; k0 += 64) {
        bf16x8 av[4], bv[4];
#pragma unroll
        for (int i = 0; i < 4; ++i) {
            int row = i * 32 + sr;
            av[i] = *(const bf16x8*)(A + (size_t)(mBase + row) * K + k0 + sc * 8);
            bv[i] = *(const bf16x8*)(Bt + (size_t)(nBase + row) * K + k0 + sc * 8);
        }
        __syncthreads();
#pragma unroll
        for (int i = 0; i < 4; ++i) {
            int row = i * 32 + sr;
            int off = row * 128 + ((sc * 16) ^ ((row & 7) << 4));
            *(bf16x8*)(Asw + off) = av[i];
            *(bf16x8*)(Bsw + off) = bv[i];
        }
        __syncthreads();
#pragma unroll
        for (int kk = 0; kk < 2; ++kk) {
            bf16x8 af[4], bfr[4];
            int kb = kk * 64 + hi * 16;
#pragma unroll
            for (int q = 0; q < 4; ++q) {
                int rowA = wm * 64 + q * 16 + lo;
                af[q] = *(const bf16x8*)(Asw + rowA * 128 + (kb ^ ((rowA & 7) << 4)));
                int rowB = wn * 64 + q * 16 + lo;
                bfr[q] = *(const bf16x8*)(Bsw + rowB * 128 + (kb ^ ((rowB & 7) << 4)));
            }
#pragma unroll
            for (int fm = 0; fm < 4; ++fm)
#pragma unroll
                for (int fn = 0; fn < 4; ++fn)
                    acc[fm][fn] = __builtin_amdgcn_mfma_f32_16x16x32_bf16(af[fm], bfr[fn], acc[fm][fn], 0, 0, 0);
        }
    }

    // C/D layout (HW-verified): col = lane&15, row = (lane>>4)*4 + reg
#pragma unroll
    for (int fm = 0; fm < 4; ++fm) {
        int m0 = mBase + wm * 64 + fm * 16 + hi * 4;
#pragma unroll
        for (int fn = 0; fn < 4; ++fn) {
            int n = nBase + wn * 64 + fn * 16 + lo;
            float bb = bias ? bias[n] : 0.0f;
#pragma unroll
            for (int rr = 0; rr < 4; ++rr) {
                float v = acc[fm][fn][rr] + bb;
                if (fuse_lrelu) v = lrelu(v);
                C[(size_t)(m0 + rr) * N + n] = f2bf(v);
            }
        }
    }
}

// ---------------- edge aggregate: x[n] = lrelu(U[n] - V[n] + bias[b] + max_k V[idx_k]) ----------------
__global__ __launch_bounds__(256) void edge_max(const short* __restrict__ UV, const int* __restrict__ idx,
                                                const float* __restrict__ bias, short* __restrict__ out,
                                                int F, int lf /* log2(F/8) */) {
    int gid = blockIdx.x * 256 + threadIdx.x;
    int n = gid >> lf;
    int f = (gid & ((F >> 3) - 1)) << 3;
    int b = n >> 11;
    int F2 = F << 1;
    const short* base = UV + (size_t)n * F2;
    bf16x8 u8 = *(const bf16x8*)(base + f);
    bf16x8 v8 = *(const bf16x8*)(base + F + f);
    const int* ip = idx + (size_t)n * 8;
    float mx[8];
#pragma unroll
    for (int j = 0; j < 8; ++j) mx[j] = -FLT_MAX;
#pragma unroll
    for (int k = 0; k < 8; ++k) {
        bf16x8 w8 = *(const bf16x8*)(UV + (size_t)ip[k] * F2 + F + f);
#pragma unroll
        for (int j = 0; j < 8; ++j) mx[j] = fmaxf(mx[j], b2f(w8[j]));
    }
    const float* bp = bias + (size_t)b * F + f;
    bf16x8 z;
#pragma unroll
    for (int j = 0; j < 8; ++j)
        z[j] = f2bf(lrelu(b2f(u8[j]) - b2f(v8[j]) + bp[j] + mx[j]));
    *(bf16x8*)(out + (size_t)n * F + f) = z;
}

// ---------------- final: out = x + hf @ Wf2 + bf2 ----------------
__global__ __launch_bounds__(256) void final_out(const short* __restrict__ hf, const float* __restrict__ Wf2,
                                                 const float* __restrict__ bf2, const float* __restrict__ x,
                                                 float* __restrict__ out) {
    int n = blockIdx.x * 256 + threadIdx.x;
    const short* h = hf + (size_t)n * 256;
    float s0 = bf2[0], s1 = bf2[1], s2 = bf2[2];
    for (int k8 = 0; k8 < 32; ++k8) {
        bf16x8 hv = *(const bf16x8*)(h + k8 * 8);
        const float* w = Wf2 + k8 * 24;
#pragma unroll
        for (int j = 0; j < 8; ++j) {
            float hh = b2f(hv[j]);
            s0 = fmaf(hh, w[j * 3 + 0], s0);
            s1 = fmaf(hh, w[j * 3 + 1], s1);
            s2 = fmaf(hh, w[j * 3 + 2], s2);
        }
    }
    out[n * 3 + 0] = x[n * 3 + 0] + s0;
    out[n * 3 + 1] = x[n * 3 + 1] + s1;
    out[n * 3 + 2] = x[n * 3 + 2] + s2;
}

extern "C" void kernel_launch(void* const* d_in, const int* in_sizes, int n_in,
                              void* d_out, int out_size, void* d_ws, size_t ws_size,
                              hipStream_t stream) {
    const float* x    = (const float*)d_in[0];
    const float* beta = (const float*)d_in[1];
    const float* ctxv = (const float*)d_in[2];
    const float* cond = (const float*)d_in[3];
    const float* W0   = (const float*)d_in[4];
    const float* b0   = (const float*)d_in[5];
    const float* ln_g = (const float*)d_in[6];
    const float* ln_b = (const float*)d_in[7];
    const float* W1   = (const float*)d_in[8];
    const float* b1   = (const float*)d_in[9];
    const float* W2   = (const float*)d_in[10];
    const float* b2   = (const float*)d_in[11];
    const float* W3   = (const float*)d_in[12];
    const float* b3   = (const float*)d_in[13];
    const float* Wf1  = (const float*)d_in[14];
    const float* bf1  = (const float*)d_in[15];
    const float* Wf2  = (const float*)d_in[16];
    const float* bf2  = (const float*)d_in[17];
    float* out = (float*)d_out;

    char* ws = (char*)d_ws;
    size_t off = 0;
    auto alloc = [&](size_t bytes) -> void* {
        void* p = ws + off;
        off += bytes;
        off = (off + 511) & ~(size_t)511;
        return p;
    };

    int*   idx    = (int*)alloc((size_t)M * 8 * 4);
    int*   fcount = (int*)alloc(4);
    int*   flist  = (int*)alloc((size_t)M * 4);
    float* ctx   = (float*)alloc((size_t)BATCH * CTXW * 4);
    float* bias1 = (float*)alloc((size_t)BATCH * 128 * 4);
    float* bias2 = (float*)alloc((size_t)BATCH * 256 * 4);
    float* bias3 = (float*)alloc((size_t)BATCH * 512 * 4);
    short* W1p   = (short*)alloc((size_t)256 * 64 * 2);
    short* W2p   = (short*)alloc((size_t)512 * 128 * 2);
    short* W3p   = (short*)alloc((size_t)1024 * 256 * 2);
    short* Wf1p  = (short*)alloc((size_t)256 * 512 * 2);
    short* R1    = (short*)alloc((size_t)M * 1024 * 2);  // feat0, later UV3
    short* R2    = (short*)alloc((size_t)M * 512 * 2);   // UV1, UV2, x3
    short* R3    = (short*)alloc((size_t)M * 256 * 2);   // x1, hf
    short* R4    = (short*)alloc((size_t)M * 256 * 2);   // x2

    short* feat0 = R1;
    short* UV1 = R2;  short* x1 = R3;
    short* UV2 = R2;  short* x2 = R4;
    short* UV3 = R1;  short* x3 = R2;
    short* hf  = R3;

    zero1<<<1, 1, 0, stream>>>(fcount);
    build_ctx<<<BATCH, 256, 0, stream>>>(beta, ctxv, cond, ctx);
    ctx_bias_all<<<dim3(14, BATCH), 256, 0, stream>>>(ctx, W1, b1, W2, b2, W3, b3, bias1, bias2, bias3);
    pack_all<<<(475136 + 255) / 256, 256, 0, stream>>>(W1, W2, W3, Wf1, W1p, W2p, W3p, Wf1p);

    knn_sel<<<dim3(NPTS / 4, BATCH), 256, 0, stream>>>(x, idx, flist, fcount);
    init_ln<<<M * 64 / 256, 256, 0, stream>>>(x, W0, b0, ln_g, ln_b, feat0);
    knn64_redo<<<256, 256, 0, stream>>>(x, flist, fcount, idx);

    gemm_mfma<<<dim3(M / 128, 2), 256, 0, stream>>>(feat0, W1p, UV1, 256, 64, nullptr, 0);
    edge_max<<<M * 16 / 256, 256, 0, stream>>>(UV1, idx, bias1, x1, 128, 4);

    gemm_mfma<<<dim3(M / 128, 4), 256, 0, stream>>>(x1, W2p, UV2, 512, 128, nullptr, 0);
    edge_max<<<M * 32 / 256, 256, 0, stream>>>(UV2, idx, bias2, x2, 256, 5);

    gemm_mfma<<<dim3(M / 128, 8), 256, 0, stream>>>(x2, W3p, UV3, 1024, 256, nullptr, 0);
    edge_max<<<M * 64 / 256, 256, 0, stream>>>(UV3, idx, bias3, x3, 512, 6);

    gemm_mfma<<<dim3(M / 128, 2), 256, 0, stream>>>(x3, Wf1p, hf, 256, 512, bf1, 1);

    final_out<<<M / 256, 256, 0, stream>>>(hf, Wf2, bf2, x, out);
}

// Round 7
// 219.131 us; speedup vs baseline: 2.7943x; 1.1926x over previous
//
#include <hip/hip_runtime.h>
#include <cfloat>

constexpr int BATCH = 8, NPTS = 2048;
constexpr int M = BATCH * NPTS;   // 16384 nodes
constexpr int CTXW = 515;

typedef __attribute__((ext_vector_type(8))) short bf16x8;
typedef __attribute__((ext_vector_type(4))) float f32x4;

__device__ __forceinline__ float lrelu(float v) { return v > 0.0f ? v : 0.2f * v; }
__device__ __forceinline__ float b2f(short u) {
    return __uint_as_float(((unsigned int)(unsigned short)u) << 16);
}
__device__ __forceinline__ short f2bf(float f) {
    unsigned int u = __float_as_uint(f);
    return (short)((u + 0x7FFF + ((u >> 16) & 1)) >> 16);
}
// async global->LDS, 16B per lane; lds dest = wave-uniform base + lane*16
__device__ __forceinline__ void gl16(const void* g, void* l) {
    __builtin_amdgcn_global_load_lds((const __attribute__((address_space(1))) unsigned int*)g,
                                     (__attribute__((address_space(3))) unsigned int*)l,
                                     16, 0, 0);
}

// ---------------- ctx vector (+ fcount zeroing) ----------------
__global__ void build_ctx(const float* __restrict__ beta, const float* __restrict__ ctxv,
                          const float* __restrict__ cond, float* __restrict__ ctx,
                          int* __restrict__ fcount) {
    int b = blockIdx.x;
    if (b == 0 && threadIdx.x == 0) *fcount = 0;
    float be = beta[b];
    for (int i = threadIdx.x; i < CTXW; i += blockDim.x) {
        float v;
        if (i == 0) v = be;
        else if (i == 1) v = sinf(be);
        else if (i == 2) v = cosf(be);
        else if (i < 259) v = ctxv[b * 256 + (i - 3)];
        else v = cond[b * 256 + (i - 259)];
        ctx[b * CTXW + i] = v;
    }
}

// fused: bias_ctx for layers 1..3; grid (14, BATCH)
__global__ __launch_bounds__(256) void ctx_bias_all(const float* __restrict__ ctx,
        const float* __restrict__ W1, const float* __restrict__ b1,
        const float* __restrict__ W2, const float* __restrict__ b2,
        const float* __restrict__ W3, const float* __restrict__ b3,
        float* __restrict__ bias1, float* __restrict__ bias2, float* __restrict__ bias3) {
    int b = blockIdx.y, blk = blockIdx.x;
    const float *W, *bv; float* out; int rowOff, F, fblk;
    if (blk < 2)      { W = W1; bv = b1; out = bias1; rowOff = 128; F = 128; fblk = blk; }
    else if (blk < 6) { W = W2; bv = b2; out = bias2; rowOff = 256; F = 256; fblk = blk - 2; }
    else              { W = W3; bv = b3; out = bias3; rowOff = 512; F = 512; fblk = blk - 6; }
    int fl = threadIdx.x >> 2, ks = threadIdx.x & 3;
    int f = fblk * 64 + fl;
    const float* c = ctx + b * CTXW;
    const float* w = W + (size_t)rowOff * F + f;
    float s = 0.f;
    for (int i = ks; i < CTXW; i += 4) s = fmaf(c[i], w[(size_t)i * F], s);
    s += __shfl_xor(s, 1);
    s += __shfl_xor(s, 2);
    if (ks == 0) out[(size_t)b * F + f] = s + bv[f];
}

// fused weight pack (transposed bf16): W1p(256x64) W2p(512x128) W3p(1024x256) Wf1p(256x512)
__global__ void pack_all(const float* __restrict__ W1, const float* __restrict__ W2,
                         const float* __restrict__ W3, const float* __restrict__ Wf1,
                         short* __restrict__ W1p, short* __restrict__ W2p,
                         short* __restrict__ W3p, short* __restrict__ Wf1p) {
    int gid = blockIdx.x * 256 + threadIdx.x;
    if (gid < 16384) {
        int j = gid >> 6, k = gid & 63;
        float v = (j < 128) ? W1[(size_t)k * 128 + j] : W1[(size_t)(64 + k) * 128 + (j - 128)];
        W1p[gid] = f2bf(v);
    } else if (gid < 81920) {
        int g = gid - 16384; int j = g >> 7, k = g & 127;
        float v = (j < 256) ? W2[(size_t)k * 256 + j] : W2[(size_t)(128 + k) * 256 + (j - 256)];
        W2p[g] = f2bf(v);
    } else if (gid < 344064) {
        int g = gid - 81920; int j = g >> 8, k = g & 255;
        float v = (j < 512) ? W3[(size_t)k * 512 + j] : W3[(size_t)(256 + k) * 512 + (j - 512)];
        W3p[g] = f2bf(v);
    } else if (gid < 475136) {
        int g = gid - 344064; int f = g >> 9, k = g & 511;
        Wf1p[g] = f2bf(Wf1[(size_t)k * 256 + f]);
    }
}

// ---------------- kNN: one wave per node, composite-key min-extraction ----------------
// key = (d_bits & ~2047) | candidate_index: u32 order == (trunc d, index) lexicographic.
// 9 passes of {31-op register min-tree + 6-step shfl-min butterfly + equality exclusion}.
// Truncation adds <=2.4e-4 rel ordering error -> gap-eps 1e-3 rel, exact fp64 redo.
__global__ __launch_bounds__(256) void knn_sel(const float* __restrict__ x, int* __restrict__ idx,
                                               int* __restrict__ flist, int* __restrict__ fcount) {
    __shared__ float4 xs4[NPTS];  // 32768 B
    int b = blockIdx.y;
    const float* xb = x + (size_t)b * NPTS * 3;
    int tid = threadIdx.x;
    for (int i = tid; i < NPTS; i += 256)
        xs4[i] = make_float4(xb[i * 3], xb[i * 3 + 1], xb[i * 3 + 2], 0.f);
    __syncthreads();

    int w = tid >> 6, l = tid & 63;
    int n = blockIdx.x * 4 + w;
    float4 me = xs4[n];
    unsigned key[32];
#pragma unroll
    for (int j = 0; j < 32; ++j) {
        int m = j * 64 + l;
        float4 c = xs4[m];
        float dx = me.x - c.x, dy = me.y - c.y, dz = me.z - c.z;
        float d = fmaf(dx, dx, fmaf(dy, dy, dz * dz));
        unsigned k = (__float_as_uint(d) & 0xFFFFF800u) | (unsigned)m;
        key[j] = (m == n) ? 0xFFFFFFFFu : k;
    }

    unsigned win[9];
#pragma unroll
    for (int p = 0; p < 9; ++p) {
        unsigned m16[16], m8[8], m4[4], m2[2];
#pragma unroll
        for (int j = 0; j < 16; ++j) m16[j] = min(key[2 * j], key[2 * j + 1]);
#pragma unroll
        for (int j = 0; j < 8; ++j) m8[j] = min(m16[2 * j], m16[2 * j + 1]);
#pragma unroll
        for (int j = 0; j < 4; ++j) m4[j] = min(m8[2 * j], m8[2 * j + 1]);
        m2[0] = min(m4[0], m4[1]); m2[1] = min(m4[2], m4[3]);
        unsigned bk = min(m2[0], m2[1]);
#pragma unroll
        for (int off = 32; off > 0; off >>= 1)
            bk = min(bk, (unsigned)__shfl_xor((unsigned)bk, off));
        win[p] = bk;
        if (p < 8) {
#pragma unroll
            for (int j = 0; j < 32; ++j)
                key[j] = (key[j] == bk) ? 0xFFFFFFFFu : key[j];
        }
    }
    if (l == 0) {
        int gn = b * NPTS + n;
#pragma unroll
        for (int p = 0; p < 8; ++p)
            idx[(size_t)gn * 8 + p] = b * NPTS + (int)(win[p] & 2047u);
        float d8 = __uint_as_float(win[7] & 0xFFFFF800u);
        float d9 = __uint_as_float(win[8] & 0xFFFFF800u);
        if (d9 - d8 <= 1e-3f * d9) {   // ambiguity band (trunc+fp32 err ~5e-4 rel)
            int pp = atomicAdd(fcount, 1);
            flist[pp] = gn;
        }
    }
}

// ---------------- kNN pass 2: exact fp64 redo for flagged nodes (rare) ----------------
__global__ __launch_bounds__(256) void knn64_redo(const float* __restrict__ x, const int* __restrict__ flist,
                                                  const int* __restrict__ fcount, int* __restrict__ idx) {
    __shared__ double sd[2048];
    __shared__ int    si[2048];
    __shared__ double s2d[128];
    __shared__ int    s2i[128];
    int cnt = *fcount;
    int tid = threadIdx.x;
    for (int it = blockIdx.x; it < cnt; it += gridDim.x) {
        int gn = flist[it];
        int b = gn >> 11, n = gn & 2047;
        const float* xb = x + (size_t)b * NPTS * 3;
        float n0 = xb[n * 3], n1 = xb[n * 3 + 1], n2 = xb[n * 3 + 2];
        double sqn = ((double)n0 * n0 + (double)n1 * n1) + (double)n2 * n2;
        double bd[8]; int bidx[8];
#pragma unroll
        for (int k = 0; k < 8; ++k) { bd[k] = DBL_MAX; bidx[k] = 0; }
        for (int j = 0; j < 8; ++j) {
            int m = tid * 8 + j;           // ascending index order per thread (stable ties)
            float c0 = xb[m * 3], c1 = xb[m * 3 + 1], c2 = xb[m * 3 + 2];
            double sqm = ((double)c0 * c0 + (double)c1 * c1) + (double)c2 * c2;
            double dot = ((double)n0 * c0 + (double)n1 * c1) + (double)n2 * c2;
            double d = (sqn + sqm) - 2.0 * dot;
            if (m == n) continue;
            if (d < bd[7]) {
                double cd = d; int ci = m;
#pragma unroll
                for (int q = 0; q < 8; ++q) {
                    if (cd < bd[q]) {
                        double td = bd[q]; bd[q] = cd; cd = td;
                        int ti = bidx[q]; bidx[q] = ci; ci = ti;
                    }
                }
            }
        }
#pragma unroll
        for (int k = 0; k < 8; ++k) { sd[tid * 8 + k] = bd[k]; si[tid * 8 + k] = bidx[k]; }
        __syncthreads();
        if (tid < 16) {
            double fb[8]; int fi[8];
#pragma unroll
            for (int k = 0; k < 8; ++k) { fb[k] = DBL_MAX; fi[k] = 0; }
            for (int t = tid * 16; t < tid * 16 + 16; ++t) {
                for (int k = 0; k < 8; ++k) {
                    double d = sd[t * 8 + k];
                    if (d >= fb[7]) break;
                    int ci = si[t * 8 + k];
                    double cd = d;
#pragma unroll
                    for (int q = 0; q < 8; ++q) {
                        if (cd < fb[q]) {
                            double td = fb[q]; fb[q] = cd; cd = td;
                            int ti = fi[q]; fi[q] = ci; ci = ti;
                        }
                    }
                }
            }
#pragma unroll
            for (int k = 0; k < 8; ++k) { s2d[tid * 8 + k] = fb[k]; s2i[tid * 8 + k] = fi[k]; }
        }
        __syncthreads();
        if (tid == 0) {
            double fb[8]; int fi[8];
#pragma unroll
            for (int k = 0; k < 8; ++k) { fb[k] = DBL_MAX; fi[k] = 0; }
            for (int t = 0; t < 16; ++t) {
                for (int k = 0; k < 8; ++k) {
                    double d = s2d[t * 8 + k];
                    if (d >= fb[7]) break;
                    int ci = s2i[t * 8 + k];
                    double cd = d;
#pragma unroll
                    for (int q = 0; q < 8; ++q) {
                        if (cd < fb[q]) {
                            double td = fb[q]; fb[q] = cd; cd = td;
                            int ti = fi[q]; fi[q] = ci; ci = ti;
                        }
                    }
                }
            }
#pragma unroll
            for (int k = 0; k < 8; ++k) idx[(size_t)gn * 8 + k] = b * NPTS + fi[k];
        }
        __syncthreads();
    }
}

// ---------------- init MLP + LayerNorm -> bf16 feat ----------------
__global__ __launch_bounds__(256) void init_ln(const float* __restrict__ x, const float* __restrict__ W0,
                                               const float* __restrict__ b0, const float* __restrict__ g,
                                               const float* __restrict__ be, short* __restrict__ feat) {
    int t = blockIdx.x * 256 + threadIdx.x;
    int node = t >> 6, c = t & 63;
    const float* xp = x + (size_t)node * 3;
    float h = fmaf(xp[0], W0[c], fmaf(xp[1], W0[64 + c], fmaf(xp[2], W0[128 + c], b0[c])));
    h = lrelu(h);
    float s = h;
#pragma unroll
    for (int o = 32; o > 0; o >>= 1) s += __shfl_xor(s, o);
    float mu = s * (1.0f / 64.0f);
    float tt = h - mu;
    float q = tt * tt;
#pragma unroll
    for (int o = 32; o > 0; o >>= 1) q += __shfl_xor(q, o);
    float var = q * (1.0f / 64.0f);
    feat[t] = f2bf(tt * rsqrtf(var + 1e-5f) * g[c] + be[c]);
}

// ---------------- bf16 MFMA GEMM: C(MxN) = A(MxK) @ Bt(NxK)^T, 128x128 tile, BK=64 ----------------
// Staging: global_load_lds width=16, linear LDS dest, inverse-swizzled global source
// (LDS[row][c] holds global chunk c ^ (row&7); read side XORs the same pattern).
__global__ __launch_bounds__(256) void gemm_mfma(const short* __restrict__ A, const short* __restrict__ Bt,
                                                 short* __restrict__ C, int N, int K,
                                                 const float* __restrict__ bias, int fuse_lrelu) {
    __shared__ __align__(16) char Asw[128 * 128];
    __shared__ __align__(16) char Bsw[128 * 128];
    int tid = threadIdx.x;
    int lane = tid & 63, wid = tid >> 6;
    int wm = wid >> 1, wn = wid & 1;
    int mBase = blockIdx.x * 128, nBase = blockIdx.y * 128;
    int lo = lane & 15, hi = lane >> 4;

    f32x4 acc[4][4];
#pragma unroll
    for (int i = 0; i < 4; ++i)
#pragma unroll
        for (int j = 0; j < 4; ++j) acc[i][j] = (f32x4){0.f, 0.f, 0.f, 0.f};

    int w8 = lane >> 3, c8 = lane & 7;
    int swz = ((c8 ^ w8) << 4);               // source byte offset within 128B row
    const char* Ab = (const char*)A;
    const char* Bb = (const char*)Bt;
    size_t strideB = (size_t)K * 2;

    for (int k0 = 0; k0 < K; k0 += 64) {
        __syncthreads();   // prior iter's ds_reads complete before DMA overwrite
#pragma unroll
        for (int i = 0; i < 4; ++i) {
            int r0 = wid * 32 + i * 8;        // wave-uniform row base (8 rows/call)
            gl16(Ab + (size_t)(mBase + r0 + w8) * strideB + k0 * 2 + swz, Asw + r0 * 128);
            gl16(Bb + (size_t)(nBase + r0 + w8) * strideB + k0 * 2 + swz, Bsw + r0 * 128);
        }
        __syncthreads();   // compiler drains vmcnt before barrier
#pragma unroll
        for (int kk = 0; kk < 2; ++kk) {
            bf16x8 af[4], bfr[4];
            int kb = kk * 64 + hi * 16;
#pragma unroll
            for (int q = 0; q < 4; ++q) {
                int rowA = wm * 64 + q * 16 + lo;
                af[q] = *(const bf16x8*)(Asw + rowA * 128 + (kb ^ ((rowA & 7) << 4)));
                int rowB = wn * 64 + q * 16 + lo;
                bfr[q] = *(const bf16x8*)(Bsw + rowB * 128 + (kb ^ ((rowB & 7) << 4)));
            }
#pragma unroll
            for (int fm = 0; fm < 4; ++fm)
#pragma unroll
                for (int fn = 0; fn < 4; ++fn)
                    acc[fm][fn] = __builtin_amdgcn_mfma_f32_16x16x32_bf16(af[fm], bfr[fn], acc[fm][fn], 0, 0, 0);
        }
    }

    // C/D layout (HW-verified): col = lane&15, row = (lane>>4)*4 + reg
#pragma unroll
    for (int fm = 0; fm < 4; ++fm) {
        int m0 = mBase + wm * 64 + fm * 16 + hi * 4;
#pragma unroll
        for (int fn = 0; fn < 4; ++fn) {
            int n = nBase + wn * 64 + fn * 16 + lo;
            float bb = bias ? bias[n] : 0.0f;
#pragma unroll
            for (int rr = 0; rr < 4; ++rr) {
                float v = acc[fm][fn][rr] + bb;
                if (fuse_lrelu) v = lrelu(v);
                C[(size_t)(m0 + rr) * N + n] = f2bf(v);
            }
        }
    }
}

// ---------------- edge aggregate: x[n] = lrelu(U[n] - V[n] + bias[b] + max_k V[idx_k]) ----------------
// XCD-affinity block swizzle: contiguous 1/8 chunks of the grid (== whole batches)
// land on one XCD so each batch's V-panel stays in that XCD's private L2.
__global__ __launch_bounds__(256) void edge_max(const short* __restrict__ UV, const int* __restrict__ idx,
                                                const float* __restrict__ bias, short* __restrict__ out,
                                                int F, int lf /* log2(F/8) */) {
    int nblk = gridDim.x;
    int bid = blockIdx.x;
    int bid2 = (bid & 7) * (nblk >> 3) + (bid >> 3);
    int gid = bid2 * 256 + threadIdx.x;
    int n = gid >> lf;
    int f = (gid & ((F >> 3) - 1)) << 3;
    int b = n >> 11;
    int F2 = F << 1;
    const short* base = UV + (size_t)n * F2;
    bf16x8 u8 = *(const bf16x8*)(base + f);
    bf16x8 v8 = *(const bf16x8*)(base + F + f);
    const int* ip = idx + (size_t)n * 8;
    float mx[8];
#pragma unroll
    for (int j = 0; j < 8; ++j) mx[j] = -FLT_MAX;
#pragma unroll
    for (int k = 0; k < 8; ++k) {
        bf16x8 w8 = *(const bf16x8*)(UV + (size_t)ip[k] * F2 + F + f);
#pragma unroll
        for (int j = 0; j < 8; ++j) mx[j] = fmaxf(mx[j], b2f(w8[j]));
    }
    const float* bp = bias + (size_t)b * F + f;
    bf16x8 z;
#pragma unroll
    for (int j = 0; j < 8; ++j)
        z[j] = f2bf(lrelu(b2f(u8[j]) - b2f(v8[j]) + bp[j] + mx[j]));
    *(bf16x8*)(out + (size_t)n * F + f) = z;
}

// ---------------- final: out = x + hf @ Wf2 + bf2 ----------------
__global__ __launch_bounds__(256) void final_out(const short* __restrict__ hf, const float* __restrict__ Wf2,
                                                 const float* __restrict__ bf2, const float* __restrict__ x,
                                                 float* __restrict__ out) {
    int n = blockIdx.x * 256 + threadIdx.x;
    const short* h = hf + (size_t)n * 256;
    float s0 = bf2[0], s1 = bf2[1], s2 = bf2[2];
    for (int k8 = 0; k8 < 32; ++k8) {
        bf16x8 hv = *(const bf16x8*)(h + k8 * 8);
        const float* w = Wf2 + k8 * 24;
#pragma unroll
        for (int j = 0; j < 8; ++j) {
            float hh = b2f(hv[j]);
            s0 = fmaf(hh, w[j * 3 + 0], s0);
            s1 = fmaf(hh, w[j * 3 + 1], s1);
            s2 = fmaf(hh, w[j * 3 + 2], s2);
        }
    }
    out[n * 3 + 0] = x[n * 3 + 0] + s0;
    out[n * 3 + 1] = x[n * 3 + 1] + s1;
    out[n * 3 + 2] = x[n * 3 + 2] + s2;
}

extern "C" void kernel_launch(void* const* d_in, const int* in_sizes, int n_in,
                              void* d_out, int out_size, void* d_ws, size_t ws_size,
                              hipStream_t stream) {
    const float* x    = (const float*)d_in[0];
    const float* beta = (const float*)d_in[1];
    const float* ctxv = (const float*)d_in[2];
    const float* cond = (const float*)d_in[3];
    const float* W0   = (const float*)d_in[4];
    const float* b0   = (const float*)d_in[5];
    const float* ln_g = (const float*)d_in[6];
    const float* ln_b = (const float*)d_in[7];
    const float* W1   = (const float*)d_in[8];
    const float* b1   = (const float*)d_in[9];
    const float* W2   = (const float*)d_in[10];
    const float* b2   = (const float*)d_in[11];
    const float* W3   = (const float*)d_in[12];
    const float* b3   = (const float*)d_in[13];
    const float* Wf1  = (const float*)d_in[14];
    const float* bf1  = (const float*)d_in[15];
    const float* Wf2  = (const float*)d_in[16];
    const float* bf2  = (const float*)d_in[17];
    float* out = (float*)d_out;

    char* ws = (char*)d_ws;
    size_t off = 0;
    auto alloc = [&](size_t bytes) -> void* {
        void* p = ws + off;
        off += bytes;
        off = (off + 511) & ~(size_t)511;
        return p;
    };

    int*   idx    = (int*)alloc((size_t)M * 8 * 4);
    int*   fcount = (int*)alloc(4);
    int*   flist  = (int*)alloc((size_t)M * 4);
    float* ctx   = (float*)alloc((size_t)BATCH * CTXW * 4);
    float* bias1 = (float*)alloc((size_t)BATCH * 128 * 4);
    float* bias2 = (float*)alloc((size_t)BATCH * 256 * 4);
    float* bias3 = (float*)alloc((size_t)BATCH * 512 * 4);
    short* W1p   = (short*)alloc((size_t)256 * 64 * 2);
    short* W2p   = (short*)alloc((size_t)512 * 128 * 2);
    short* W3p   = (short*)alloc((size_t)1024 * 256 * 2);
    short* Wf1p  = (short*)alloc((size_t)256 * 512 * 2);
    short* R1    = (short*)alloc((size_t)M * 1024 * 2);  // feat0, later UV3
    short* R2    = (short*)alloc((size_t)M * 512 * 2);   // UV1, UV2, x3
    short* R3    = (short*)alloc((size_t)M * 256 * 2);   // x1, hf
    short* R4    = (short*)alloc((size_t)M * 256 * 2);   // x2

    short* feat0 = R1;
    short* UV1 = R2;  short* x1 = R3;
    short* UV2 = R2;  short* x2 = R4;
    short* UV3 = R1;  short* x3 = R2;
    short* hf  = R3;

    build_ctx<<<BATCH, 256, 0, stream>>>(beta, ctxv, cond, ctx, fcount);
    ctx_bias_all<<<dim3(14, BATCH), 256, 0, stream>>>(ctx, W1, b1, W2, b2, W3, b3, bias1, bias2, bias3);
    pack_all<<<(475136 + 255) / 256, 256, 0, stream>>>(W1, W2, W3, Wf1, W1p, W2p, W3p, Wf1p);

    knn_sel<<<dim3(NPTS / 4, BATCH), 256, 0, stream>>>(x, idx, flist, fcount);
    init_ln<<<M * 64 / 256, 256, 0, stream>>>(x, W0, b0, ln_g, ln_b, feat0);
    knn64_redo<<<256, 256, 0, stream>>>(x, flist, fcount, idx);

    gemm_mfma<<<dim3(M / 128, 2), 256, 0, stream>>>(feat0, W1p, UV1, 256, 64, nullptr, 0);
    edge_max<<<M * 16 / 256, 256, 0, stream>>>(UV1, idx, bias1, x1, 128, 4);

    gemm_mfma<<<dim3(M / 128, 4), 256, 0, stream>>>(x1, W2p, UV2, 512, 128, nullptr, 0);
    edge_max<<<M * 32 / 256, 256, 0, stream>>>(UV2, idx, bias2, x2, 256, 5);

    gemm_mfma<<<dim3(M / 128, 8), 256, 0, stream>>>(x2, W3p, UV3, 1024, 256, nullptr, 0);
    edge_max<<<M * 64 / 256, 256, 0, stream>>>(UV3, idx, bias3, x3, 512, 6);

    gemm_mfma<<<dim3(M / 128, 2), 256, 0, stream>>>(x3, Wf1p, hf, 256, 512, bf1, 1);

    final_out<<<M / 256, 256, 0, stream>>>(hf, Wf2, bf2, x, out);
}